// Round 1
// baseline (1030.100 us; speedup 1.0000x reference)
//
#include <hip/hip_runtime.h>
#include <math.h>

#define B_  8
#define S_  2048
#define D_  256
#define H_  4
#define DH  64
#define M_  (B_ * S_)          // 16384 rows
#define QS  4194304            // M_ * D_ elements

// ---------------------------------------------------------------------------
// Generic tiled fp32 GEMM: C[m,n] = sum_k A[m,k] * W[n,k] + bias[n]  (+res)
// MODE 0: plain (A, lda=K)
// MODE 1: concat A (k<256 from A, k>=256 from A2; both lda=256), K must be 512
// MODE 2: plain + residual add from res[m*256 + n] (N tile count covers 256)
// Tiles: BM=BN=64, BK=64. 256 threads, 4x4 microtile per thread.
// LDS stored transposed (k-major) so compute reads are ds_read_b128.
// ---------------------------------------------------------------------------
template <int MODE>
__global__ __launch_bounds__(256) void gemm_kernel(
    const float* __restrict__ A, const float* __restrict__ A2,
    const float* __restrict__ W, const float* __restrict__ bias,
    const float* __restrict__ res, float* __restrict__ C,
    int K, int ldc)
{
    __shared__ float Ast[64][68];   // [k][m]
    __shared__ float Wst[64][68];   // [k][n]
    const int tid = threadIdx.x;
    const int m0  = blockIdx.x * 64;
    const int n0  = blockIdx.y * 64;
    const int tm4 = (tid >> 4) * 4;
    const int tn4 = (tid & 15) * 4;

    float acc[4][4] = {};

    for (int k0 = 0; k0 < K; k0 += 64) {
        const float* Asrc;
        int lda, kbase;
        if (MODE == 1) {
            Asrc  = (k0 < 256) ? A : A2;
            lda   = 256;
            kbase = k0 & 255;
        } else {
            Asrc  = A;
            lda   = K;
            kbase = k0;
        }
#pragma unroll
        for (int i = 0; i < 4; i++) {
            const int idx = i * 256 + tid;
            const int r   = idx >> 4;          // row within tile (m or n)
            const int k4  = (idx & 15) * 4;    // k offset
            const float4 av = *(const float4*)(Asrc + (size_t)(m0 + r) * lda + kbase + k4);
            Ast[k4 + 0][r] = av.x; Ast[k4 + 1][r] = av.y;
            Ast[k4 + 2][r] = av.z; Ast[k4 + 3][r] = av.w;
            const float4 wv = *(const float4*)(W + (size_t)(n0 + r) * K + k0 + k4);
            Wst[k4 + 0][r] = wv.x; Wst[k4 + 1][r] = wv.y;
            Wst[k4 + 2][r] = wv.z; Wst[k4 + 3][r] = wv.w;
        }
        __syncthreads();
#pragma unroll 16
        for (int k = 0; k < 64; k++) {
            const float4 a  = *(const float4*)&Ast[k][tm4];
            const float4 b  = *(const float4*)&Wst[k][tn4];
            const float ar[4] = {a.x, a.y, a.z, a.w};
            const float br[4] = {b.x, b.y, b.z, b.w};
#pragma unroll
            for (int i = 0; i < 4; i++)
#pragma unroll
                for (int j = 0; j < 4; j++) acc[i][j] += ar[i] * br[j];
        }
        __syncthreads();
    }

    const float4 b4 = *(const float4*)(bias + n0 + tn4);
    const float bb[4] = {b4.x, b4.y, b4.z, b4.w};
#pragma unroll
    for (int i = 0; i < 4; i++) {
        const int m = m0 + tm4 + i;
        float o[4];
#pragma unroll
        for (int j = 0; j < 4; j++) o[j] = acc[i][j] + bb[j];
        if (MODE == 2) {
            const float4 r4 = *(const float4*)(res + (size_t)m * 256 + n0 + tn4);
            o[0] += r4.x; o[1] += r4.y; o[2] += r4.z; o[3] += r4.w;
        }
        *(float4*)(C + (size_t)m * ldc + n0 + tn4) = make_float4(o[0], o[1], o[2], o[3]);
    }
}

// ---------------------------------------------------------------------------
// Rope + de-interleave: qkv_buf [M,768] (layout h*192 + d*3 + c) ->
// q/k/v [B,H,S,Dh]; rope on q,k; q pre-scaled by Dh^-0.5 = 0.125.
// keypoints: [2,B,1,S,Dh]: cos at (b*S+s)*64+d, sin at +B*S*64.
// ---------------------------------------------------------------------------
__global__ __launch_bounds__(256) void rope_kernel(
    const float* __restrict__ qkv, const float* __restrict__ kp,
    float* __restrict__ q, float* __restrict__ k, float* __restrict__ v)
{
    const int m = blockIdx.x;      // b*S + s
    const int b = m >> 11;
    const int s = m & 2047;
    const float* row = qkv + (size_t)m * 768;
#pragma unroll
    for (int i = 0; i < 3; i++) {
        const int idx = i * 256 + threadIdx.x;
        const int h = idx / 192;
        const int r = idx - h * 192;
        const int d = r / 3;
        const int c = r - d * 3;
        const float val  = row[idx];
        const size_t oidx = ((size_t)(b * H_ + h) * S_ + s) * DH + d;
        if (c == 2) {
            v[oidx] = val;
        } else {
            const float pair = row[h * 192 + (d ^ 1) * 3 + c];
            const float rot  = (d & 1) ? pair : -pair;
            const size_t kidx = ((size_t)b * S_ + s) * DH + d;
            const float cs = kp[kidx];
            const float sn = kp[(size_t)B_ * S_ * DH + kidx];
            const float out = val * cs + rot * sn;
            if (c == 0) q[oidx] = out * 0.125f;
            else        k[oidx] = out;
        }
    }
}

// ---------------------------------------------------------------------------
// Flash attention, fp32. Grid (B*H, S/64). Block 256 threads.
// 64 q-rows per block, online softmax over 64-key chunks.
// LDS: qst/kst transposed [d][row] for b128 reads; vs row-major [kc][d].
// P reuses the kst buffer (extra barrier) to stay under 64 KB LDS.
// ---------------------------------------------------------------------------
__global__ __launch_bounds__(256) void attn_kernel(
    const float* __restrict__ q, const float* __restrict__ k,
    const float* __restrict__ v, float* __restrict__ ctx)
{
    __shared__ float qst[64][68];   // [d][qr]
    __shared__ float kst[64][68];   // [d][kc]; reused as Pst[kc][qr]
    __shared__ float vs[64][68];    // [kc][d]
    const int tid = threadIdx.x;
    const int bh  = blockIdx.x;     // 0..31
    const int q0  = blockIdx.y * 64;
    const int b   = bh >> 2;
    const int h   = bh & 3;
    const float* qbase = q + (size_t)bh * S_ * DH;
    const float* kbase = k + (size_t)bh * S_ * DH;
    const float* vbase = v + (size_t)bh * S_ * DH;

#pragma unroll
    for (int i = 0; i < 4; i++) {
        const int idx = i * 256 + tid;
        const int m  = idx >> 4;
        const int d4 = (idx & 15) * 4;
        const float4 av = *(const float4*)(qbase + (size_t)(q0 + m) * DH + d4);
        qst[d4 + 0][m] = av.x; qst[d4 + 1][m] = av.y;
        qst[d4 + 2][m] = av.z; qst[d4 + 3][m] = av.w;
    }

    const int qr4 = (tid >> 4) * 4;     // 4 q-rows owned by this thread
    const int c4  = (tid & 15) * 4;     // 4 k-cols (scores) / 4 d-cols (output)
    float o[4][4] = {};
    float mrun[4] = {-1e30f, -1e30f, -1e30f, -1e30f};
    float lrun[4] = {};

    for (int kb = 0; kb < S_ / 64; kb++) {
        __syncthreads();   // prev iter fully done before overwriting kst/vs
        const int k0 = kb * 64;
#pragma unroll
        for (int i = 0; i < 4; i++) {
            const int idx = i * 256 + tid;
            const int kc = idx >> 4;
            const int d4 = (idx & 15) * 4;
            const float4 kv4 = *(const float4*)(kbase + (size_t)(k0 + kc) * DH + d4);
            kst[d4 + 0][kc] = kv4.x; kst[d4 + 1][kc] = kv4.y;
            kst[d4 + 2][kc] = kv4.z; kst[d4 + 3][kc] = kv4.w;
            const float4 vv4 = *(const float4*)(vbase + (size_t)(k0 + kc) * DH + d4);
            *(float4*)&vs[kc][d4] = vv4;
        }
        __syncthreads();

        float s4[4][4] = {};
#pragma unroll 8
        for (int d = 0; d < 64; d++) {
            const float4 a  = *(const float4*)&qst[d][qr4];
            const float4 bk = *(const float4*)&kst[d][c4];
            const float ar[4] = {a.x, a.y, a.z, a.w};
            const float br[4] = {bk.x, bk.y, bk.z, bk.w};
#pragma unroll
            for (int i = 0; i < 4; i++)
#pragma unroll
                for (int j = 0; j < 4; j++) s4[i][j] += ar[i] * br[j];
        }

        // online softmax (q already carries the 0.125 scale)
        float p[4][4];
#pragma unroll
        for (int i = 0; i < 4; i++) {
            float mx = fmaxf(fmaxf(s4[i][0], s4[i][1]), fmaxf(s4[i][2], s4[i][3]));
            mx = fmaxf(mx, __shfl_xor(mx, 1));
            mx = fmaxf(mx, __shfl_xor(mx, 2));
            mx = fmaxf(mx, __shfl_xor(mx, 4));
            mx = fmaxf(mx, __shfl_xor(mx, 8));
            const float mnew  = fmaxf(mrun[i], mx);
            const float alpha = __expf(mrun[i] - mnew);
            float rs = 0.f;
#pragma unroll
            for (int j = 0; j < 4; j++) { p[i][j] = __expf(s4[i][j] - mnew); rs += p[i][j]; }
            rs += __shfl_xor(rs, 1);
            rs += __shfl_xor(rs, 2);
            rs += __shfl_xor(rs, 4);
            rs += __shfl_xor(rs, 8);
            lrun[i] = lrun[i] * alpha + rs;
            mrun[i] = mnew;
#pragma unroll
            for (int j = 0; j < 4; j++) o[i][j] *= alpha;
        }

        __syncthreads();   // all QK reads of kst done
#pragma unroll
        for (int j = 0; j < 4; j++)   // Pst[kc][qr] into kst storage
            *(float4*)&kst[c4 + j][qr4] = make_float4(p[0][j], p[1][j], p[2][j], p[3][j]);
        __syncthreads();   // P visible

#pragma unroll 8
        for (int kc = 0; kc < 64; kc++) {
            const float4 a  = *(const float4*)&kst[kc][qr4];  // P[qr][kc]
            const float4 bv = *(const float4*)&vs[kc][c4];    // V[kc][dc]
            const float ar[4] = {a.x, a.y, a.z, a.w};
            const float br[4] = {bv.x, bv.y, bv.z, bv.w};
#pragma unroll
            for (int i = 0; i < 4; i++)
#pragma unroll
                for (int j = 0; j < 4; j++) o[i][j] += ar[i] * br[j];
        }
    }

#pragma unroll
    for (int i = 0; i < 4; i++) {
        const float inv = 1.f / lrun[i];
        float4 ov = make_float4(o[i][0] * inv, o[i][1] * inv, o[i][2] * inv, o[i][3] * inv);
        *(float4*)(ctx + ((size_t)b * S_ + q0 + qr4 + i) * D_ + h * DH + c4) = ov;
    }
}

// ---------------------------------------------------------------------------
// LayerNorm (over 512) + exact GELU, in place. One block per row.
// ---------------------------------------------------------------------------
__global__ __launch_bounds__(256) void ln_gelu_kernel(
    float* __restrict__ x, const float* __restrict__ g, const float* __restrict__ bt)
{
    __shared__ float ss[4], sqs[4];
    const int m = blockIdx.x;
    float* row = x + (size_t)m * 512;
    const int t = threadIdx.x;
    const float v0 = row[t];
    const float v1 = row[t + 256];
    float s  = v0 + v1;
    float sq = v0 * v0 + v1 * v1;
#pragma unroll
    for (int off = 1; off < 64; off <<= 1) {
        s  += __shfl_xor(s, off);
        sq += __shfl_xor(sq, off);
    }
    const int w = t >> 6;
    if ((t & 63) == 0) { ss[w] = s; sqs[w] = sq; }
    __syncthreads();
    s  = ss[0] + ss[1] + ss[2] + ss[3];
    sq = sqs[0] + sqs[1] + sqs[2] + sqs[3];
    const float mu   = s * (1.f / 512.f);
    const float var  = sq * (1.f / 512.f) - mu * mu;
    const float rstd = rsqrtf(var + 1e-5f);

    float y0 = (v0 - mu) * rstd * g[t] + bt[t];
    float y1 = (v1 - mu) * rstd * g[t + 256] + bt[t + 256];
    row[t]       = 0.5f * y0 * (1.f + erff(y0 * 0.70710678118654752f));
    row[t + 256] = 0.5f * y1 * (1.f + erff(y1 * 0.70710678118654752f));
}

// ---------------------------------------------------------------------------
extern "C" void kernel_launch(void* const* d_in, const int* in_sizes, int n_in,
                              void* d_out, int out_size, void* d_ws, size_t ws_size,
                              hipStream_t stream)
{
    const float* desc   = (const float*)d_in[0];
    const float* kp     = (const float*)d_in[1];
    const float* Wqkv_w = (const float*)d_in[2];
    const float* Wqkv_b = (const float*)d_in[3];
    const float* Wo_w   = (const float*)d_in[4];
    const float* Wo_b   = (const float*)d_in[5];
    const float* W1_w   = (const float*)d_in[6];
    const float* W1_b   = (const float*)d_in[7];
    const float* ln_g   = (const float*)d_in[8];
    const float* ln_b   = (const float*)d_in[9];
    const float* W2_w   = (const float*)d_in[10];
    const float* W2_b   = (const float*)d_in[11];
    float* out = (float*)d_out;
    float* ws  = (float*)d_ws;

    // workspace layout (floats): [0,3QS) qkv_buf -> later reused as x1 [0,2QS)
    // and msg [2QS,3QS); q/k/v at 3/4/5 QS; ctx at 6QS. Total 7*QS = 117 MB.
    float* qkv_buf = ws;
    float* qb  = ws + 3 * (size_t)QS;
    float* kb  = ws + 4 * (size_t)QS;
    float* vb  = ws + 5 * (size_t)QS;
    float* ctx = ws + 6 * (size_t)QS;
    float* x1  = ws;                      // reuse (qkv_buf dead after rope)
    float* msg = ws + 2 * (size_t)QS;     // reuse

    const dim3 blk(256);

    // 1) QKV projection: [M,256] @ [768,256]^T -> [M,768]
    gemm_kernel<0><<<dim3(M_ / 64, 768 / 64), blk, 0, stream>>>(
        desc, nullptr, Wqkv_w, Wqkv_b, nullptr, qkv_buf, 256, 768);

    // 2) rope + scatter to q/k/v [B,H,S,Dh], q scaled by 0.125
    rope_kernel<<<dim3(M_), blk, 0, stream>>>(qkv_buf, kp, qb, kb, vb);

    // 3) flash attention -> ctx [B,S,D]
    attn_kernel<<<dim3(B_ * H_, S_ / 64), blk, 0, stream>>>(qb, kb, vb, ctx);

    // 4) output projection: ctx @ Wo^T -> msg [M,256]
    gemm_kernel<0><<<dim3(M_ / 64, 256 / 64), blk, 0, stream>>>(
        ctx, nullptr, Wo_w, Wo_b, nullptr, msg, 256, 256);

    // 5) W1 on concat(desc, msg): [M,512] @ [512,512]^T -> x1 [M,512]
    gemm_kernel<1><<<dim3(M_ / 64, 512 / 64), blk, 0, stream>>>(
        desc, msg, W1_w, W1_b, nullptr, x1, 512, 512);

    // 6) LayerNorm + GELU in place
    ln_gelu_kernel<<<dim3(M_), blk, 0, stream>>>(x1, ln_g, ln_b);

    // 7) W2 + bias + residual -> out: [M,512] @ [256,512]^T + desc
    gemm_kernel<2><<<dim3(M_ / 64, 256 / 64), blk, 0, stream>>>(
        x1, nullptr, W2_w, W2_b, desc, out, 512, 256);
}

// Round 2
// 662.264 us; speedup vs baseline: 1.5554x; 1.5554x over previous
//
#include <hip/hip_runtime.h>
#include <math.h>

#define B_  8
#define S_  2048
#define D_  256
#define H_  4
#define DH  64
#define M_  (B_ * S_)          // 16384 rows
#define QS  4194304            // M_ * D_ elements
#define LQ  72                 // LDS row stride (bf16 elems): 144B, 16B-aligned

typedef __attribute__((ext_vector_type(8))) short bf16x8;   // 8 bf16 = 4 VGPRs
typedef __attribute__((ext_vector_type(4))) float f32x4;

__device__ __forceinline__ unsigned short f2bf(float x) {
    union { float f; unsigned int u; } c; c.f = x;
    unsigned int r = (c.u + 0x7fffu + ((c.u >> 16) & 1u)) >> 16;   // RNE
    return (unsigned short)r;
}

// ---------------------------------------------------------------------------
// Generic tiled fp32 GEMM: C[m,n] = sum_k A[m,k] * W[n,k] + bias[n]  (+res)
// MODE 0: plain; MODE 1: concat A (K=512); MODE 2: plain + residual.
// ---------------------------------------------------------------------------
template <int MODE>
__global__ __launch_bounds__(256) void gemm_kernel(
    const float* __restrict__ A, const float* __restrict__ A2,
    const float* __restrict__ W, const float* __restrict__ bias,
    const float* __restrict__ res, float* __restrict__ C,
    int K, int ldc)
{
    __shared__ float Ast[64][68];   // [k][m]
    __shared__ float Wst[64][68];   // [k][n]
    const int tid = threadIdx.x;
    const int m0  = blockIdx.x * 64;
    const int n0  = blockIdx.y * 64;
    const int tm4 = (tid >> 4) * 4;
    const int tn4 = (tid & 15) * 4;

    float acc[4][4] = {};

    for (int k0 = 0; k0 < K; k0 += 64) {
        const float* Asrc;
        int lda, kbase;
        if (MODE == 1) {
            Asrc  = (k0 < 256) ? A : A2;
            lda   = 256;
            kbase = k0 & 255;
        } else {
            Asrc  = A;
            lda   = K;
            kbase = k0;
        }
#pragma unroll
        for (int i = 0; i < 4; i++) {
            const int idx = i * 256 + tid;
            const int r   = idx >> 4;
            const int k4  = (idx & 15) * 4;
            const float4 av = *(const float4*)(Asrc + (size_t)(m0 + r) * lda + kbase + k4);
            Ast[k4 + 0][r] = av.x; Ast[k4 + 1][r] = av.y;
            Ast[k4 + 2][r] = av.z; Ast[k4 + 3][r] = av.w;
            const float4 wv = *(const float4*)(W + (size_t)(n0 + r) * K + k0 + k4);
            Wst[k4 + 0][r] = wv.x; Wst[k4 + 1][r] = wv.y;
            Wst[k4 + 2][r] = wv.z; Wst[k4 + 3][r] = wv.w;
        }
        __syncthreads();
#pragma unroll 16
        for (int k = 0; k < 64; k++) {
            const float4 a  = *(const float4*)&Ast[k][tm4];
            const float4 b  = *(const float4*)&Wst[k][tn4];
            const float ar[4] = {a.x, a.y, a.z, a.w};
            const float br[4] = {b.x, b.y, b.z, b.w};
#pragma unroll
            for (int i = 0; i < 4; i++)
#pragma unroll
                for (int j = 0; j < 4; j++) acc[i][j] += ar[i] * br[j];
        }
        __syncthreads();
    }

    const float4 b4 = *(const float4*)(bias + n0 + tn4);
    const float bb[4] = {b4.x, b4.y, b4.z, b4.w};
#pragma unroll
    for (int i = 0; i < 4; i++) {
        const int m = m0 + tm4 + i;
        float o[4];
#pragma unroll
        for (int j = 0; j < 4; j++) o[j] = acc[i][j] + bb[j];
        if (MODE == 2) {
            const float4 r4 = *(const float4*)(res + (size_t)m * 256 + n0 + tn4);
            o[0] += r4.x; o[1] += r4.y; o[2] += r4.z; o[3] += r4.w;
        }
        *(float4*)(C + (size_t)m * ldc + n0 + tn4) = make_float4(o[0], o[1], o[2], o[3]);
    }
}

// ---------------------------------------------------------------------------
// Rope + de-interleave -> bf16 q/k/v [B,H,S,Dh]; q pre-scaled by 0.125.
// ---------------------------------------------------------------------------
__global__ __launch_bounds__(256) void rope_kernel(
    const float* __restrict__ qkv, const float* __restrict__ kp,
    unsigned short* __restrict__ q, unsigned short* __restrict__ k,
    unsigned short* __restrict__ v)
{
    const int m = blockIdx.x;      // b*S + s
    const int b = m >> 11;
    const int s = m & 2047;
    const float* row = qkv + (size_t)m * 768;
#pragma unroll
    for (int i = 0; i < 3; i++) {
        const int idx = i * 256 + threadIdx.x;
        const int h = idx / 192;
        const int r = idx - h * 192;
        const int d = r / 3;
        const int c = r - d * 3;
        const float val  = row[idx];
        const size_t oidx = ((size_t)(b * H_ + h) * S_ + s) * DH + d;
        if (c == 2) {
            v[oidx] = f2bf(val);
        } else {
            const float pair = row[h * 192 + (d ^ 1) * 3 + c];
            const float rot  = (d & 1) ? pair : -pair;
            const size_t kidx = ((size_t)b * S_ + s) * DH + d;
            const float cs = kp[kidx];
            const float sn = kp[(size_t)B_ * S_ * DH + kidx];
            const float out = val * cs + rot * sn;
            if (c == 0) q[oidx] = f2bf(out * 0.125f);
            else        k[oidx] = f2bf(out);
        }
    }
}

// ---------------------------------------------------------------------------
// Flash attention, bf16 MFMA (16x16x32). Grid (B*H, S/64), 256 threads.
// Wave w owns q-rows [16w,16w+16). Verified layouts (m89/m120):
//   A[m=lane&15][k=quad*8+j], B[k=quad*8+j][n=lane&15],
//   C/D: col=lane&15, row=quad*4+reg.
// P round-trips through LDS (C-layout -> A-layout). V transposed in LDS.
// All LDS tiles row-stride LQ=72 bf16 (16B-aligned rows, even bank spread).
// ---------------------------------------------------------------------------
__global__ __launch_bounds__(256) void attn_kernel(
    const unsigned short* __restrict__ q, const unsigned short* __restrict__ k,
    const unsigned short* __restrict__ v, float* __restrict__ ctx)
{
    __shared__ unsigned short qs [64 * LQ];   // [m][d]
    __shared__ unsigned short ks [64 * LQ];   // [key][d]
    __shared__ unsigned short vts[64 * LQ];   // [d][key] (transposed)
    __shared__ unsigned short ps [64 * LQ];   // [m][key]

    const int tid  = threadIdx.x;
    const int w    = tid >> 6;
    const int lane = tid & 63;
    const int n    = lane & 15;
    const int quad = lane >> 4;
    const int bh   = blockIdx.x;
    const int q0   = blockIdx.y * 64;
    const int b    = bh >> 2;
    const int h    = bh & 3;

    const unsigned short* qbase = q + (size_t)bh * S_ * DH;
    const unsigned short* kbase = k + (size_t)bh * S_ * DH;
    const unsigned short* vbase = v + (size_t)bh * S_ * DH;

    // stage Q tile [m][d]
#pragma unroll
    for (int it = 0; it < 2; it++) {
        const int idx = it * 256 + tid;          // 0..511
        const int row = idx >> 3;
        const int c8  = (idx & 7) * 8;
        *(uint4*)&qs[row * LQ + c8] =
            *(const uint4*)(qbase + (size_t)(q0 + row) * DH + c8);
    }
    __syncthreads();

    bf16x8 qf[2];
    qf[0] = *(const bf16x8*)&qs[(16 * w + n) * LQ +  0 + quad * 8];
    qf[1] = *(const bf16x8*)&qs[(16 * w + n) * LQ + 32 + quad * 8];

    f32x4 o[4];
#pragma unroll
    for (int j = 0; j < 4; j++) o[j] = (f32x4){0.f, 0.f, 0.f, 0.f};
    float mrun[4] = {-1e30f, -1e30f, -1e30f, -1e30f};
    float lrun[4] = {0.f, 0.f, 0.f, 0.f};

    for (int kb = 0; kb < S_ / 64; kb++) {
        __syncthreads();   // prior iter's K/V reads done before overwrite
        const int k0 = kb * 64;
#pragma unroll
        for (int it = 0; it < 2; it++) {
            const int idx = it * 256 + tid;
            const int row = idx >> 3;
            const int c8  = (idx & 7) * 8;
            *(uint4*)&ks[row * LQ + c8] =
                *(const uint4*)(kbase + (size_t)(k0 + row) * DH + c8);
            const uint4 vv = *(const uint4*)(vbase + (size_t)(k0 + row) * DH + c8);
            const unsigned short* us = (const unsigned short*)&vv;
#pragma unroll
            for (int i = 0; i < 8; i++) vts[(c8 + i) * LQ + row] = us[i];
        }
        __syncthreads();

        // S = Q · K^T   (q carries the 0.125 scale)
        f32x4 sacc[4];
#pragma unroll
        for (int j = 0; j < 4; j++) sacc[j] = (f32x4){0.f, 0.f, 0.f, 0.f};
#pragma unroll
        for (int t = 0; t < 2; t++) {
#pragma unroll
            for (int j = 0; j < 4; j++) {
                const bf16x8 kf = *(const bf16x8*)&ks[(16 * j + n) * LQ + t * 32 + quad * 8];
                sacc[j] = __builtin_amdgcn_mfma_f32_16x16x32_bf16(qf[t], kf, sacc[j], 0, 0, 0);
            }
        }

        // online softmax; rows quad*4+r, cols 16j+n
#pragma unroll
        for (int r = 0; r < 4; r++) {
            float mx = fmaxf(fmaxf(sacc[0][r], sacc[1][r]), fmaxf(sacc[2][r], sacc[3][r]));
            mx = fmaxf(mx, __shfl_xor(mx, 1));
            mx = fmaxf(mx, __shfl_xor(mx, 2));
            mx = fmaxf(mx, __shfl_xor(mx, 4));
            mx = fmaxf(mx, __shfl_xor(mx, 8));
            const float mnew  = fmaxf(mrun[r], mx);
            const float alpha = __expf(mrun[r] - mnew);
            mrun[r] = mnew;
            float p[4], rs = 0.f;
#pragma unroll
            for (int j = 0; j < 4; j++) { p[j] = __expf(sacc[j][r] - mnew); rs += p[j]; }
            rs += __shfl_xor(rs, 1);
            rs += __shfl_xor(rs, 2);
            rs += __shfl_xor(rs, 4);
            rs += __shfl_xor(rs, 8);
            lrun[r] = lrun[r] * alpha + rs;
#pragma unroll
            for (int j = 0; j < 4; j++) {
                o[j][r] *= alpha;
                ps[(16 * w + quad * 4 + r) * LQ + 16 * j + n] = f2bf(p[j]);
            }
        }
        // ps rows [16w,16w+16) are wave-private: no cross-wave sync needed.

        // O += P · V
#pragma unroll
        for (int t = 0; t < 2; t++) {
            const bf16x8 pf = *(const bf16x8*)&ps[(16 * w + n) * LQ + t * 32 + quad * 8];
#pragma unroll
            for (int j = 0; j < 4; j++) {
                const bf16x8 vf = *(const bf16x8*)&vts[(16 * j + n) * LQ + t * 32 + quad * 8];
                o[j] = __builtin_amdgcn_mfma_f32_16x16x32_bf16(pf, vf, o[j], 0, 0, 0);
            }
        }
    }

#pragma unroll
    for (int r = 0; r < 4; r++) {
        const float inv = 1.f / lrun[r];
        const int row = q0 + 16 * w + quad * 4 + r;
#pragma unroll
        for (int j = 0; j < 4; j++)
            ctx[((size_t)b * S_ + row) * D_ + h * DH + 16 * j + n] = o[j][r] * inv;
    }
}

// ---------------------------------------------------------------------------
// LayerNorm (over 512) + exact GELU, in place. One block per row.
// ---------------------------------------------------------------------------
__global__ __launch_bounds__(256) void ln_gelu_kernel(
    float* __restrict__ x, const float* __restrict__ g, const float* __restrict__ bt)
{
    __shared__ float ss[4], sqs[4];
    const int m = blockIdx.x;
    float* row = x + (size_t)m * 512;
    const int t = threadIdx.x;
    const float v0 = row[t];
    const float v1 = row[t + 256];
    float s  = v0 + v1;
    float sq = v0 * v0 + v1 * v1;
#pragma unroll
    for (int off = 1; off < 64; off <<= 1) {
        s  += __shfl_xor(s, off);
        sq += __shfl_xor(sq, off);
    }
    const int w = t >> 6;
    if ((t & 63) == 0) { ss[w] = s; sqs[w] = sq; }
    __syncthreads();
    s  = ss[0] + ss[1] + ss[2] + ss[3];
    sq = sqs[0] + sqs[1] + sqs[2] + sqs[3];
    const float mu   = s * (1.f / 512.f);
    const float var  = sq * (1.f / 512.f) - mu * mu;
    const float rstd = rsqrtf(var + 1e-5f);

    float y0 = (v0 - mu) * rstd * g[t] + bt[t];
    float y1 = (v1 - mu) * rstd * g[t + 256] + bt[t + 256];
    row[t]       = 0.5f * y0 * (1.f + erff(y0 * 0.70710678118654752f));
    row[t + 256] = 0.5f * y1 * (1.f + erff(y1 * 0.70710678118654752f));
}

// ---------------------------------------------------------------------------
extern "C" void kernel_launch(void* const* d_in, const int* in_sizes, int n_in,
                              void* d_out, int out_size, void* d_ws, size_t ws_size,
                              hipStream_t stream)
{
    const float* desc   = (const float*)d_in[0];
    const float* kp     = (const float*)d_in[1];
    const float* Wqkv_w = (const float*)d_in[2];
    const float* Wqkv_b = (const float*)d_in[3];
    const float* Wo_w   = (const float*)d_in[4];
    const float* Wo_b   = (const float*)d_in[5];
    const float* W1_w   = (const float*)d_in[6];
    const float* W1_b   = (const float*)d_in[7];
    const float* ln_g   = (const float*)d_in[8];
    const float* ln_b   = (const float*)d_in[9];
    const float* W2_w   = (const float*)d_in[10];
    const float* W2_b   = (const float*)d_in[11];
    float* out = (float*)d_out;
    float* ws  = (float*)d_ws;

    // workspace (floats): [0,3QS) qkv_buf -> later x1 [0,2QS) + msg [2QS,3QS);
    // bf16 q/k/v at 3/4/5 QS (half-used); ctx at 6QS. Total 7*QS = 117 MB.
    float* qkv_buf = ws;
    unsigned short* qb = (unsigned short*)(ws + 3 * (size_t)QS);
    unsigned short* kb = (unsigned short*)(ws + 4 * (size_t)QS);
    unsigned short* vb = (unsigned short*)(ws + 5 * (size_t)QS);
    float* ctx = ws + 6 * (size_t)QS;
    float* x1  = ws;
    float* msg = ws + 2 * (size_t)QS;

    const dim3 blk(256);

    // 1) QKV projection: [M,256] @ [768,256]^T -> [M,768]
    gemm_kernel<0><<<dim3(M_ / 64, 768 / 64), blk, 0, stream>>>(
        desc, nullptr, Wqkv_w, Wqkv_b, nullptr, qkv_buf, 256, 768);

    // 2) rope + scatter to bf16 q/k/v [B,H,S,Dh], q scaled by 0.125
    rope_kernel<<<dim3(M_), blk, 0, stream>>>(qkv_buf, kp, qb, kb, vb);

    // 3) flash attention (bf16 MFMA) -> ctx [B,S,D] fp32
    attn_kernel<<<dim3(B_ * H_, S_ / 64), blk, 0, stream>>>(qb, kb, vb, ctx);

    // 4) output projection: ctx @ Wo^T -> msg [M,256]
    gemm_kernel<0><<<dim3(M_ / 64, 256 / 64), blk, 0, stream>>>(
        ctx, nullptr, Wo_w, Wo_b, nullptr, msg, 256, 256);

    // 5) W1 on concat(desc, msg): [M,512] @ [512,512]^T -> x1 [M,512]
    gemm_kernel<1><<<dim3(M_ / 64, 512 / 64), blk, 0, stream>>>(
        desc, msg, W1_w, W1_b, nullptr, x1, 512, 512);

    // 6) LayerNorm + GELU in place
    ln_gelu_kernel<<<dim3(M_), blk, 0, stream>>>(x1, ln_g, ln_b);

    // 7) W2 + bias + residual -> out: [M,512] @ [256,512]^T + desc
    gemm_kernel<2><<<dim3(M_ / 64, 256 / 64), blk, 0, stream>>>(
        x1, nullptr, W2_w, W2_b, desc, out, 512, 256);
}

// Round 3
// 372.101 us; speedup vs baseline: 2.7683x; 1.7798x over previous
//
#include <hip/hip_runtime.h>
#include <math.h>

#define B_  8
#define S_  2048
#define D_  256
#define H_  4
#define DH  64
#define M_  (B_ * S_)          // 16384 rows
#define QS  4194304            // M_ * D_ elements
#define LQ  72                 // attn LDS row stride (bf16): 144B, 16B-aligned

typedef __attribute__((ext_vector_type(8))) short bf16x8;   // 8 bf16 = 4 VGPRs
typedef __attribute__((ext_vector_type(4))) float f32x4;
typedef unsigned short u16;

#define AS1 __attribute__((address_space(1)))
#define AS3 __attribute__((address_space(3)))

__device__ __forceinline__ u16 f2bf(float x) {
    union { float f; unsigned int u; } c; c.f = x;
    unsigned int r = (c.u + 0x7fffu + ((c.u >> 16) & 1u)) >> 16;   // RNE
    return (u16)r;
}

// async global->LDS, 16B per lane; LDS dest = wave-uniform base + lane*16
__device__ __forceinline__ void gload16(const void* g, void* l) {
    __builtin_amdgcn_global_load_lds((const AS1 unsigned int*)g,
                                     (AS3 unsigned int*)l, 16, 0, 0);
}

// ---------------------------------------------------------------------------
// fp32 -> bf16 cast, 4 elems/thread. n must be divisible by 1024.
// ---------------------------------------------------------------------------
__global__ __launch_bounds__(256) void cast_kernel(
    const float* __restrict__ s, u16* __restrict__ d)
{
    const int i = (blockIdx.x * 256 + threadIdx.x) * 4;
    const float4 v = *(const float4*)(s + i);
    u16 o[4] = {f2bf(v.x), f2bf(v.y), f2bf(v.z), f2bf(v.w)};
    *(uint2*)(d + i) = *(const uint2*)o;
}

// ---------------------------------------------------------------------------
// bf16 MFMA GEMM (m97 structure): C[m,n] = sum_k A[m,k]*W[n,k] + bias[n]
// 128x128 tile, BK=64, 256 thr (4 waves, 2x2 wave grid, 64x64 acc each).
// CONCAT: A from {A,A2} (both lda=256, K=512). RES: += res. OUTBF16: bf16 C.
// Staging via global_load_lds w=16 into unpadded row-major LDS [r][64].
// ---------------------------------------------------------------------------
template <int CONCAT, int RES, int OUTBF16>
__global__ __launch_bounds__(256) void gemm_bf16(
    const u16* __restrict__ A, const u16* __restrict__ A2,
    const u16* __restrict__ W, const float* __restrict__ bias,
    const float* __restrict__ res, float* __restrict__ Cf,
    u16* __restrict__ Cb, int K, int N)
{
    __shared__ u16 As[128 * 64];
    __shared__ u16 Bs[128 * 64];
    const int tid  = threadIdx.x;
    const int w    = tid >> 6;
    const int lane = tid & 63;
    const int n    = lane & 15;
    const int quad = lane >> 4;
    const int m0   = blockIdx.x * 128;
    const int n0   = blockIdx.y * 128;
    const int m_off = (w >> 1) * 64;
    const int n_off = (w & 1) * 64;
    const int lrow = lane >> 3;          // 0..7
    const int lcol = (lane & 7) * 8;     // bf16 elem offset

    f32x4 acc[4][4];
#pragma unroll
    for (int i = 0; i < 4; i++)
#pragma unroll
        for (int j = 0; j < 4; j++) acc[i][j] = (f32x4){0.f, 0.f, 0.f, 0.f};

    for (int k0 = 0; k0 < K; k0 += 64) {
        const u16* Asrc;
        int kb, lda;
        if (CONCAT) { Asrc = (k0 < 256) ? A : A2; kb = k0 & 255; lda = 256; }
        else        { Asrc = A; kb = k0; lda = K; }

        __syncthreads();   // prior compute's LDS reads done
#pragma unroll
        for (int it = 0; it < 4; it++) {
            const int r0 = it * 32 + w * 8;      // wave-uniform
            gload16(Asrc + (size_t)(m0 + r0 + lrow) * lda + kb + lcol, &As[r0 * 64]);
            gload16(W    + (size_t)(n0 + r0 + lrow) * K   + k0 + lcol, &Bs[r0 * 64]);
        }
        __syncthreads();   // staging visible (vmcnt drained at barrier)

        bf16x8 af[4][2], bf[4][2];
#pragma unroll
        for (int mt = 0; mt < 4; mt++)
#pragma unroll
            for (int t = 0; t < 2; t++)
                af[mt][t] = *(const bf16x8*)&As[(m_off + mt * 16 + n) * 64 + t * 32 + quad * 8];
#pragma unroll
        for (int nt = 0; nt < 4; nt++)
#pragma unroll
            for (int t = 0; t < 2; t++)
                bf[nt][t] = *(const bf16x8*)&Bs[(n_off + nt * 16 + n) * 64 + t * 32 + quad * 8];

#pragma unroll
        for (int mt = 0; mt < 4; mt++)
#pragma unroll
            for (int nt = 0; nt < 4; nt++) {
                acc[mt][nt] = __builtin_amdgcn_mfma_f32_16x16x32_bf16(af[mt][0], bf[nt][0], acc[mt][nt], 0, 0, 0);
                acc[mt][nt] = __builtin_amdgcn_mfma_f32_16x16x32_bf16(af[mt][1], bf[nt][1], acc[mt][nt], 0, 0, 0);
            }
    }

    // epilogue: C/D layout col=lane&15, row=quad*4+reg
#pragma unroll
    for (int nt = 0; nt < 4; nt++) {
        const int col = n0 + n_off + nt * 16 + n;
        const float bv = bias[col];
#pragma unroll
        for (int mt = 0; mt < 4; mt++) {
#pragma unroll
            for (int r = 0; r < 4; r++) {
                const int row = m0 + m_off + mt * 16 + quad * 4 + r;
                float o = acc[mt][nt][r] + bv;
                if (RES) o += res[(size_t)row * N + col];
                if (OUTBF16) Cb[(size_t)row * N + col] = f2bf(o);
                else         Cf[(size_t)row * N + col] = o;
            }
        }
    }
}

// ---------------------------------------------------------------------------
// Rope + de-interleave -> bf16 q/k/v [B,H,S,Dh]; q pre-scaled by 0.125.
// ---------------------------------------------------------------------------
__global__ __launch_bounds__(256) void rope_kernel(
    const float* __restrict__ qkv, const float* __restrict__ kp,
    u16* __restrict__ q, u16* __restrict__ k, u16* __restrict__ v)
{
    const int m = blockIdx.x;      // b*S + s
    const int b = m >> 11;
    const int s = m & 2047;
    const float* row = qkv + (size_t)m * 768;
#pragma unroll
    for (int i = 0; i < 3; i++) {
        const int idx = i * 256 + threadIdx.x;
        const int h = idx / 192;
        const int r = idx - h * 192;
        const int d = r / 3;
        const int c = r - d * 3;
        const float val  = row[idx];
        const size_t oidx = ((size_t)(b * H_ + h) * S_ + s) * DH + d;
        if (c == 2) {
            v[oidx] = f2bf(val);
        } else {
            const float pair = row[h * 192 + (d ^ 1) * 3 + c];
            const float rot  = (d & 1) ? pair : -pair;
            const size_t kidx = ((size_t)b * S_ + s) * DH + d;
            const float cs = kp[kidx];
            const float sn = kp[(size_t)B_ * S_ * DH + kidx];
            const float out = val * cs + rot * sn;
            if (c == 0) q[oidx] = f2bf(out * 0.125f);
            else        k[oidx] = f2bf(out);
        }
    }
}

// ---------------------------------------------------------------------------
// Flash attention, bf16 MFMA (16x16x32). Grid (B*H, S/64), 256 threads.
// Unchanged from round 2 except ctx output is now bf16.
// ---------------------------------------------------------------------------
__global__ __launch_bounds__(256) void attn_kernel(
    const u16* __restrict__ q, const u16* __restrict__ k,
    const u16* __restrict__ v, u16* __restrict__ ctx)
{
    __shared__ u16 qs [64 * LQ];   // [m][d]
    __shared__ u16 ks [64 * LQ];   // [key][d]
    __shared__ u16 vts[64 * LQ];   // [d][key] (transposed)
    __shared__ u16 ps [64 * LQ];   // [m][key]

    const int tid  = threadIdx.x;
    const int w    = tid >> 6;
    const int lane = tid & 63;
    const int n    = lane & 15;
    const int quad = lane >> 4;
    const int bh   = blockIdx.x;
    const int q0   = blockIdx.y * 64;
    const int b    = bh >> 2;
    const int h    = bh & 3;

    const u16* qbase = q + (size_t)bh * S_ * DH;
    const u16* kbase = k + (size_t)bh * S_ * DH;
    const u16* vbase = v + (size_t)bh * S_ * DH;

#pragma unroll
    for (int it = 0; it < 2; it++) {
        const int idx = it * 256 + tid;          // 0..511
        const int row = idx >> 3;
        const int c8  = (idx & 7) * 8;
        *(uint4*)&qs[row * LQ + c8] =
            *(const uint4*)(qbase + (size_t)(q0 + row) * DH + c8);
    }
    __syncthreads();

    bf16x8 qf[2];
    qf[0] = *(const bf16x8*)&qs[(16 * w + n) * LQ +  0 + quad * 8];
    qf[1] = *(const bf16x8*)&qs[(16 * w + n) * LQ + 32 + quad * 8];

    f32x4 o[4];
#pragma unroll
    for (int j = 0; j < 4; j++) o[j] = (f32x4){0.f, 0.f, 0.f, 0.f};
    float mrun[4] = {-1e30f, -1e30f, -1e30f, -1e30f};
    float lrun[4] = {0.f, 0.f, 0.f, 0.f};

    for (int kb = 0; kb < S_ / 64; kb++) {
        __syncthreads();
        const int k0 = kb * 64;
#pragma unroll
        for (int it = 0; it < 2; it++) {
            const int idx = it * 256 + tid;
            const int row = idx >> 3;
            const int c8  = (idx & 7) * 8;
            *(uint4*)&ks[row * LQ + c8] =
                *(const uint4*)(kbase + (size_t)(k0 + row) * DH + c8);
            const uint4 vv = *(const uint4*)(vbase + (size_t)(k0 + row) * DH + c8);
            const u16* us = (const u16*)&vv;
#pragma unroll
            for (int i = 0; i < 8; i++) vts[(c8 + i) * LQ + row] = us[i];
        }
        __syncthreads();

        f32x4 sacc[4];
#pragma unroll
        for (int j = 0; j < 4; j++) sacc[j] = (f32x4){0.f, 0.f, 0.f, 0.f};
#pragma unroll
        for (int t = 0; t < 2; t++) {
#pragma unroll
            for (int j = 0; j < 4; j++) {
                const bf16x8 kf = *(const bf16x8*)&ks[(16 * j + n) * LQ + t * 32 + quad * 8];
                sacc[j] = __builtin_amdgcn_mfma_f32_16x16x32_bf16(qf[t], kf, sacc[j], 0, 0, 0);
            }
        }

#pragma unroll
        for (int r = 0; r < 4; r++) {
            float mx = fmaxf(fmaxf(sacc[0][r], sacc[1][r]), fmaxf(sacc[2][r], sacc[3][r]));
            mx = fmaxf(mx, __shfl_xor(mx, 1));
            mx = fmaxf(mx, __shfl_xor(mx, 2));
            mx = fmaxf(mx, __shfl_xor(mx, 4));
            mx = fmaxf(mx, __shfl_xor(mx, 8));
            const float mnew  = fmaxf(mrun[r], mx);
            const float alpha = __expf(mrun[r] - mnew);
            mrun[r] = mnew;
            float p[4], rs = 0.f;
#pragma unroll
            for (int j = 0; j < 4; j++) { p[j] = __expf(sacc[j][r] - mnew); rs += p[j]; }
            rs += __shfl_xor(rs, 1);
            rs += __shfl_xor(rs, 2);
            rs += __shfl_xor(rs, 4);
            rs += __shfl_xor(rs, 8);
            lrun[r] = lrun[r] * alpha + rs;
#pragma unroll
            for (int j = 0; j < 4; j++) {
                o[j][r] *= alpha;
                ps[(16 * w + quad * 4 + r) * LQ + 16 * j + n] = f2bf(p[j]);
            }
        }

#pragma unroll
        for (int t = 0; t < 2; t++) {
            const bf16x8 pf = *(const bf16x8*)&ps[(16 * w + n) * LQ + t * 32 + quad * 8];
#pragma unroll
            for (int j = 0; j < 4; j++) {
                const bf16x8 vf = *(const bf16x8*)&vts[(16 * j + n) * LQ + t * 32 + quad * 8];
                o[j] = __builtin_amdgcn_mfma_f32_16x16x32_bf16(pf, vf, o[j], 0, 0, 0);
            }
        }
    }

#pragma unroll
    for (int r = 0; r < 4; r++) {
        const float inv = 1.f / lrun[r];
        const int row = q0 + 16 * w + quad * 4 + r;
#pragma unroll
        for (int j = 0; j < 4; j++)
            ctx[((size_t)b * S_ + row) * D_ + h * DH + 16 * j + n] = f2bf(o[j][r] * inv);
    }
}

// ---------------------------------------------------------------------------
// LayerNorm (over 512, fp32 stats) + exact GELU -> bf16 out.
// ---------------------------------------------------------------------------
__global__ __launch_bounds__(256) void ln_gelu_kernel(
    const float* __restrict__ x, const float* __restrict__ g,
    const float* __restrict__ bt, u16* __restrict__ y)
{
    __shared__ float ss[4], sqs[4];
    const int m = blockIdx.x;
    const float* row = x + (size_t)m * 512;
    const int t = threadIdx.x;
    const float v0 = row[t];
    const float v1 = row[t + 256];
    float s  = v0 + v1;
    float sq = v0 * v0 + v1 * v1;
#pragma unroll
    for (int off = 1; off < 64; off <<= 1) {
        s  += __shfl_xor(s, off);
        sq += __shfl_xor(sq, off);
    }
    const int w = t >> 6;
    if ((t & 63) == 0) { ss[w] = s; sqs[w] = sq; }
    __syncthreads();
    s  = ss[0] + ss[1] + ss[2] + ss[3];
    sq = sqs[0] + sqs[1] + sqs[2] + sqs[3];
    const float mu   = s * (1.f / 512.f);
    const float var  = sq * (1.f / 512.f) - mu * mu;
    const float rstd = rsqrtf(var + 1e-5f);

    const float y0 = (v0 - mu) * rstd * g[t] + bt[t];
    const float y1 = (v1 - mu) * rstd * g[t + 256] + bt[t + 256];
    y[(size_t)m * 512 + t]       = f2bf(0.5f * y0 * (1.f + erff(y0 * 0.70710678118654752f)));
    y[(size_t)m * 512 + t + 256] = f2bf(0.5f * y1 * (1.f + erff(y1 * 0.70710678118654752f)));
}

// ---------------------------------------------------------------------------
extern "C" void kernel_launch(void* const* d_in, const int* in_sizes, int n_in,
                              void* d_out, int out_size, void* d_ws, size_t ws_size,
                              hipStream_t stream)
{
    const float* desc   = (const float*)d_in[0];
    const float* kp     = (const float*)d_in[1];
    const float* Wqkv_w = (const float*)d_in[2];
    const float* Wqkv_b = (const float*)d_in[3];
    const float* Wo_w   = (const float*)d_in[4];
    const float* Wo_b   = (const float*)d_in[5];
    const float* W1_w   = (const float*)d_in[6];
    const float* W1_b   = (const float*)d_in[7];
    const float* ln_g   = (const float*)d_in[8];
    const float* ln_b   = (const float*)d_in[9];
    const float* W2_w   = (const float*)d_in[10];
    const float* W2_b   = (const float*)d_in[11];
    float* out = (float*)d_out;
    float* ws  = (float*)d_ws;

    // workspace (float units; QS=4.19M). Total 6.25*QS*4 = 105 MB.
    // [0,3QS)    qkv_buf fp32; after rope reused: x1 fp32 [0,2QS), x1b bf16 [2QS,3QS)
    // [3,3.5)    qb bf16   [3.5,4) kb   [4,4.5) vb   [4.5,5) ctxb
    // [5,5.5)    descb bf16   [5.5,6) msgb bf16   [6,6.25) weight bf16 pool
    float* qkv_buf = ws;
    float* x1      = ws;
    u16*   x1b   = (u16*)(ws + 2 * (size_t)QS);
    u16*   qb    = (u16*)(ws + 3 * (size_t)QS);
    u16*   kb    = (u16*)(ws + (size_t)(3.5 * QS));
    u16*   vb    = (u16*)(ws + 4 * (size_t)QS);
    u16*   ctxb  = (u16*)(ws + (size_t)(4.5 * QS));
    u16*   descb = (u16*)(ws + 5 * (size_t)QS);
    u16*   msgb  = (u16*)(ws + (size_t)(5.5 * QS));
    u16*   wpool = (u16*)(ws + 6 * (size_t)QS);
    u16* wqkvb = wpool;                       // 768*256 = 196608
    u16* wob   = wqkvb + 196608;              // 256*256 =  65536
    u16* w1b   = wob   + 65536;               // 512*512 = 262144
    u16* w2b   = w1b   + 262144;              // 256*512 = 131072

    const dim3 blk(256);

    // 0) casts to bf16 (desc + weights)
    cast_kernel<<<dim3(QS / 1024), blk, 0, stream>>>(desc, descb);
    cast_kernel<<<dim3(196608 / 1024), blk, 0, stream>>>(Wqkv_w, wqkvb);
    cast_kernel<<<dim3(65536 / 1024), blk, 0, stream>>>(Wo_w, wob);
    cast_kernel<<<dim3(262144 / 1024), blk, 0, stream>>>(W1_w, w1b);
    cast_kernel<<<dim3(131072 / 1024), blk, 0, stream>>>(W2_w, w2b);

    // 1) QKV projection: [M,256]b @ [768,256]b^T -> fp32 [M,768]
    gemm_bf16<0, 0, 0><<<dim3(M_ / 128, 768 / 128), blk, 0, stream>>>(
        descb, nullptr, wqkvb, Wqkv_b, nullptr, qkv_buf, nullptr, 256, 768);

    // 2) rope + scatter to bf16 q/k/v [B,H,S,Dh], q scaled by 0.125
    rope_kernel<<<dim3(M_), blk, 0, stream>>>(qkv_buf, kp, qb, kb, vb);

    // 3) flash attention (bf16 MFMA) -> ctx bf16 [M,256]
    attn_kernel<<<dim3(B_ * H_, S_ / 64), blk, 0, stream>>>(qb, kb, vb, ctxb);

    // 4) output projection: ctx @ Wo^T -> msg bf16 [M,256]
    gemm_bf16<0, 0, 1><<<dim3(M_ / 128, 256 / 128), blk, 0, stream>>>(
        ctxb, nullptr, wob, Wo_b, nullptr, nullptr, msgb, 256, 256);

    // 5) W1 on concat(descb, msgb): [M,512]b @ [512,512]b^T -> fp32 x1
    gemm_bf16<1, 0, 0><<<dim3(M_ / 128, 512 / 128), blk, 0, stream>>>(
        descb, msgb, w1b, W1_b, nullptr, x1, nullptr, 512, 512);

    // 6) LayerNorm + GELU -> bf16 x1b
    ln_gelu_kernel<<<dim3(M_), blk, 0, stream>>>(x1, ln_g, ln_b, x1b);

    // 7) W2 + bias + residual(desc fp32) -> out fp32: [M,512]b @ [256,512]b^T
    gemm_bf16<0, 1, 0><<<dim3(M_ / 128, 256 / 128), blk, 0, stream>>>(
        x1b, nullptr, w2b, W2_b, desc, out, nullptr, 512, 256);
}